// Round 3
// baseline (342.947 us; speedup 1.0000x reference)
//
#include <hip/hip_runtime.h>

#define FD 128  // feature dim
#define CAP 64  // bucket slots per node (Poisson(8) degrees; P(deg>64) ~ 0)

typedef __attribute__((ext_vector_type(8))) short short8;   // 8 bf16 in 4 VGPRs
typedef __attribute__((ext_vector_type(4))) float floatx4;  // MFMA acc

__device__ inline unsigned short f2bf(float f) {  // fp32 -> bf16 bits, RNE
  unsigned u = __float_as_uint(f);
  u += 0x7fffu + ((u >> 16) & 1u);
  return (unsigned short)(u >> 16);
}
__device__ inline float lo16f(unsigned v) { return __uint_as_float(v << 16); }
__device__ inline float hi16f(unsigned v) { return __uint_as_float(v & 0xffff0000u); }
__device__ inline int imin(int a, int b) { return a < b ? a : b; }
__device__ inline unsigned umin(unsigned a, unsigned b) { return a < b ? a : b; }

// ---------------- prep: zero cursor | W swizzle->bf16 (no LDS, tiny) --------
// W frag order: idx -> k = kt*32+(lane>>4)*8+j, n = ct*16+(lane&15)
__global__ __launch_bounds__(256) void k_prep(const float* __restrict__ W,
                                              short* __restrict__ whi,
                                              int* __restrict__ cursor, int N,
                                              int zB) {
  int b = blockIdx.x;
  if (b < zB) {
    int i = b * 256 + threadIdx.x;
    if (i < N) cursor[i] = 0;
  } else {
    int idx = (b - zB) * 256 + threadIdx.x;  // 0..16383
    int j = idx & 7, lane = (idx >> 3) & 63, kt = (idx >> 9) & 3, ct = idx >> 11;
    int k = kt * 32 + (lane >> 4) * 8 + j;
    int n = ct * 16 + (lane & 15);
    whi[idx] = (short)f2bf(W[k * FD + n]);
  }
}

// ---------------- bucket fill: single atomic pass, 1 edge/thread ----------
__global__ __launch_bounds__(256) void k_fill(const int* __restrict__ src,
                                              const int* __restrict__ dst,
                                              int* __restrict__ cursor,
                                              int* __restrict__ buck, int E) {
  int e = blockIdx.x * 256 + threadIdx.x;
  if (e < E) {
    int d = dst[e], s = src[e];
    int pos = atomicAdd(&cursor[d], 1);
    if (pos < CAP) buck[(size_t)d * CAP + pos] = s;
  }
}

// ---------------- GEMM (layer 1 only): H' = dis[row] * (A_fp32 @ W) --------
__global__ __launch_bounds__(256) void k_gemm1(const float* __restrict__ A,
                                               const short* __restrict__ Wf_hi,
                                               const int* __restrict__ cursor,
                                               unsigned short* __restrict__ H, int N) {
  __shared__ short whi[FD * FD];
  int tid = threadIdx.x;
#pragma unroll
  for (int it = 0; it < 8; ++it) {
    int idx = (it * 256 + tid) * 8;  // 16 B per thread per iter
    *(short8*)&whi[idx] = *(const short8*)&Wf_hi[idx];
  }
  __syncthreads();

  int wid = tid >> 6, lane = tid & 63;
  int quad = lane >> 4, m = lane & 15;
  int rbase = blockIdx.x * 128 + wid * 32;

  short8 ahi[2][4];
#pragma unroll
  for (int t = 0; t < 2; ++t) {
    int arow = rbase + t * 16 + m;
    if (arow >= N) arow = N - 1;  // clamp; OOB rows never stored
    const float* ap = A + (size_t)arow * FD;
#pragma unroll
    for (int kt = 0; kt < 4; ++kt) {
      const float* p = ap + kt * 32 + quad * 8;
      float4 a0 = *(const float4*)p;
      float4 a1 = *(const float4*)(p + 4);
      ahi[t][kt][0] = (short)f2bf(a0.x); ahi[t][kt][1] = (short)f2bf(a0.y);
      ahi[t][kt][2] = (short)f2bf(a0.z); ahi[t][kt][3] = (short)f2bf(a0.w);
      ahi[t][kt][4] = (short)f2bf(a1.x); ahi[t][kt][5] = (short)f2bf(a1.y);
      ahi[t][kt][6] = (short)f2bf(a1.z); ahi[t][kt][7] = (short)f2bf(a1.w);
    }
  }

  float dis0[4], dis1[4];
#pragma unroll
  for (int r = 0; r < 4; ++r) {
    int row0 = imin(rbase + quad * 4 + r, N - 1);
    int row1 = imin(rbase + 16 + quad * 4 + r, N - 1);
    dis0[r] = rsqrtf((float)(imin(cursor[row0], CAP) + 1));
    dis1[r] = rsqrtf((float)(imin(cursor[row1], CAP) + 1));
  }

#pragma unroll
  for (int ct = 0; ct < 8; ++ct) {
    floatx4 acc0 = {0.f, 0.f, 0.f, 0.f}, acc1 = {0.f, 0.f, 0.f, 0.f};
#pragma unroll
    for (int kt = 0; kt < 4; ++kt) {
      int fo = (((ct << 2) + kt) * 64 + lane) * 8;
      short8 bhi = *(const short8*)&whi[fo];
      acc0 = __builtin_amdgcn_mfma_f32_16x16x32_bf16(ahi[0][kt], bhi, acc0, 0, 0, 0);
      acc1 = __builtin_amdgcn_mfma_f32_16x16x32_bf16(ahi[1][kt], bhi, acc1, 0, 0, 0);
    }
#pragma unroll
    for (int r = 0; r < 4; ++r) {
      int row0 = rbase + quad * 4 + r;
      int row1 = rbase + 16 + quad * 4 + r;
      if (row0 < N) H[(size_t)row0 * FD + ct * 16 + m] = f2bf(acc0[r] * dis0[r]);
      if (row1 < N) H[(size_t)row1 * FD + ct * 16 + m] = f2bf(acc1[r] * dis1[r]);
    }
  }
}

// ---------------- fused agg_k + gemm_{k+1} --------------------------------
// 512 thr (8 waves), 128 output rows/block. Wave w aggregates nodes
// rbase+w*16 .. +15 serially (bucket metadata prefetched 1 node ahead),
// writes relu'd bf16 rows into a 32KB XOR-swizzled LDS A-tile, syncs once,
// then runs the MFMA loop with A from LDS and dis-scaled stores to H.
// Removes per boundary: xb write + xb read + gemm A global load + 1 dispatch.
// LDS 64KB -> 2 blocks/CU -> 16 waves/CU.
__global__ __launch_bounds__(512) void k_fused(const unsigned* __restrict__ h_in,
                                               const int* __restrict__ cursor,
                                               const int* __restrict__ buck,
                                               const float* __restrict__ bias,
                                               const short* __restrict__ Wf_hi,
                                               unsigned short* __restrict__ H,
                                               int N) {
  __shared__ short whi[FD * FD];      // 32 KB weight frags
  __shared__ unsigned alds[128 * 64]; // 32 KB A-tile, u32-packed bf16, swizzled
  int tid = threadIdx.x;
#pragma unroll
  for (int it = 0; it < 4; ++it) {
    int idx = (it * 512 + tid) * 8;  // 16 B per thread per iter
    *(short8*)&whi[idx] = *(const short8*)&Wf_hi[idx];
  }
  int wid = tid >> 6, lane = tid & 63;
  int rbase = blockIdx.x * 128;
  int nbase = rbase + wid * 16;  // this wave's 16 nodes == its 16 gemm rows

  // ---- agg phase ----
  int4 psa, psb;
  int pdeg;
  {
    int node = nbase;
    if (node < N) {
      pdeg = imin(cursor[node], CAP);
      const int4* bp = (const int4*)(buck + (size_t)node * CAP);
      psa = bp[0];
      psb = bp[1];
    } else {
      pdeg = -1;
      psa = psb = make_int4(0, 0, 0, 0);
    }
  }
  for (int n = 0; n < 16; ++n) {
    int node = nbase + n;
    int4 sa = psa, sb = psb;
    int deg = __builtin_amdgcn_readfirstlane(pdeg);
    if (n < 15) {  // prefetch next node's metadata (hides cursor+bucket lat.)
      int nn = nbase + n + 1;
      if (nn < N) {
        pdeg = imin(cursor[nn], CAP);
        const int4* bp = (const int4*)(buck + (size_t)nn * CAP);
        psa = bp[0];
        psb = bp[1];
      } else {
        pdeg = -1;
      }
    }
    unsigned outw = 0;
    if (deg >= 0) {  // node < N
      float disi = rsqrtf((float)(deg + 1));
      unsigned v = h_in[(size_t)node * 64 + lane];  // self term (weight 1)
      float a0 = lo16f(v), a1 = hi16f(v);
      float b0 = 0.f, b1 = 0.f, c0 = 0.f, c1 = 0.f, d0 = 0.f, d1 = 0.f;
      const int4* bp = (const int4*)(buck + (size_t)node * CAP);
      int niter = (deg + 7) >> 3;
      for (int it = 0; it < niter; ++it) {
        if (it) {  // group 0 uses prefetched sa/sb
          sa = bp[2 * it];
          sb = bp[2 * it + 1];
        }
        int srcs[8] = {sa.x, sa.y, sa.z, sa.w, sb.x, sb.y, sb.z, sb.w};
        unsigned g[8];
#pragma unroll
        for (int j = 0; j < 8; ++j) {
          unsigned su = (unsigned)__builtin_amdgcn_readfirstlane(srcs[j]);
          su = umin(su, (unsigned)(N - 1));  // poison-safe
          g[j] = h_in[(size_t)su * 64 + lane];
        }
        int done = it * 8;
#pragma unroll
        for (int j = 0; j < 8; ++j) {
          float w = (done + j < deg) ? 1.f : 0.f;
          float l = lo16f(g[j]), hh = hi16f(g[j]);
          if (j == 0 || j == 4) { a0 = fmaf(w, l, a0); a1 = fmaf(w, hh, a1); }
          else if (j == 1 || j == 5) { b0 = fmaf(w, l, b0); b1 = fmaf(w, hh, b1); }
          else if (j == 2 || j == 6) { c0 = fmaf(w, l, c0); c1 = fmaf(w, hh, c1); }
          else { d0 = fmaf(w, l, d0); d1 = fmaf(w, hh, d1); }
        }
      }
      float2 bb = ((const float2*)bias)[lane];
      float o0 = fmaxf(fmaf(disi, (a0 + b0) + (c0 + d0), bb.x), 0.f);
      float o1 = fmaxf(fmaf(disi, (a1 + b1) + (c1 + d1), bb.y), 0.f);
      outw = ((unsigned)f2bf(o1) << 16) | (unsigned)f2bf(o0);
    }
    // swizzled LDS store: dword lane -> 16B-chunk (lane>>2) ^ (row&7)
    int lrow = wid * 16 + n;
    alds[lrow * 64 + (((lane >> 2) ^ (lrow & 7)) << 2) + (lane & 3)] = outw;
  }
  __syncthreads();

  // ---- gemm phase: wave computes rows nbase..+15 ----
  int quad = lane >> 4, m = lane & 15;
  int lrow = wid * 16 + m;
  short8 ahi[4];
#pragma unroll
  for (int kt = 0; kt < 4; ++kt) {
    int chunk = ((kt << 2) + quad) ^ (lrow & 7);  // inverse of store swizzle
    ahi[kt] = *(const short8*)&alds[lrow * 64 + chunk * 4];  // 16 B
  }
  float dis[4];
#pragma unroll
  for (int r = 0; r < 4; ++r) {
    int row = imin(nbase + quad * 4 + r, N - 1);
    dis[r] = rsqrtf((float)(imin(cursor[row], CAP) + 1));
  }
#pragma unroll
  for (int ct = 0; ct < 8; ++ct) {
    floatx4 acc = {0.f, 0.f, 0.f, 0.f};
#pragma unroll
    for (int kt = 0; kt < 4; ++kt) {
      int fo = (((ct << 2) + kt) * 64 + lane) * 8;
      short8 bhi = *(const short8*)&whi[fo];
      acc = __builtin_amdgcn_mfma_f32_16x16x32_bf16(ahi[kt], bhi, acc, 0, 0, 0);
    }
    // C/D: row = quad*4 + reg, col = lane&15
#pragma unroll
    for (int r = 0; r < 4; ++r) {
      int row = nbase + quad * 4 + r;
      if (row < N) H[(size_t)row * FD + ct * 16 + m] = f2bf(acc[r] * dis[r]);
    }
  }
}

// ---------------- final aggregation (layer 3): fp32 out --------------------
__global__ __launch_bounds__(256) void k_agg_out(const unsigned int* __restrict__ h,
                                                 const int* __restrict__ cursor,
                                                 const int* __restrict__ buck,
                                                 const float* __restrict__ bias,
                                                 float2* __restrict__ out, int N) {
  int wid = __builtin_amdgcn_readfirstlane(threadIdx.x >> 6);  // wave-uniform
  int lane = threadIdx.x & 63;
  int i = blockIdx.x * 4 + wid;
  if (i >= N) return;
  int deg = imin(cursor[i], CAP);
  float disi = rsqrtf((float)(deg + 1));
  unsigned v = h[(size_t)i * 64 + lane];  // h'_i (self term, weight 1)
  float a0 = lo16f(v), a1 = hi16f(v);
  float b0 = 0.f, b1 = 0.f, c0 = 0.f, c1 = 0.f, d0 = 0.f, d1 = 0.f;

  const int4* bp = (const int4*)(buck + (size_t)i * CAP);
  int niter = (deg + 7) >> 3;
  for (int it = 0; it < niter; ++it) {
    int4 sa = bp[2 * it];
    int4 sb = bp[2 * it + 1];
    int srcs[8] = {sa.x, sa.y, sa.z, sa.w, sb.x, sb.y, sb.z, sb.w};
    unsigned g[8];
#pragma unroll
    for (int j = 0; j < 8; ++j) {
      unsigned su = (unsigned)__builtin_amdgcn_readfirstlane(srcs[j]);
      su = umin(su, (unsigned)(N - 1));  // poison-safe
      g[j] = h[(size_t)su * 64 + lane];
    }
    int done = it * 8;
#pragma unroll
    for (int j = 0; j < 8; ++j) {
      float w = (done + j < deg) ? 1.f : 0.f;
      float l = lo16f(g[j]), hh = hi16f(g[j]);
      if (j == 0 || j == 4) { a0 = fmaf(w, l, a0); a1 = fmaf(w, hh, a1); }
      else if (j == 1 || j == 5) { b0 = fmaf(w, l, b0); b1 = fmaf(w, hh, b1); }
      else if (j == 2 || j == 6) { c0 = fmaf(w, l, c0); c1 = fmaf(w, hh, c1); }
      else { d0 = fmaf(w, l, d0); d1 = fmaf(w, hh, d1); }
    }
  }

  float2 bb = ((const float2*)bias)[lane];
  float o0 = fmaxf(fmaf(disi, (a0 + b0) + (c0 + d0), bb.x), 0.f);
  float o1 = fmaxf(fmaf(disi, (a1 + b1) + (c1 + d1), bb.y), 0.f);
  out[(size_t)i * 64 + lane] = make_float2(o0, o1);
}

// ---------------- launch ----------------

extern "C" void kernel_launch(void* const* d_in, const int* in_sizes, int n_in,
                              void* d_out, int out_size, void* d_ws, size_t ws_size,
                              hipStream_t stream) {
  const float* x = (const float*)d_in[0];
  const int* ei = (const int*)d_in[1];
  const float* Wg = (const float*)d_in[2];
  const float* b = (const float*)d_in[3];
  int N = in_sizes[0] / FD;
  int E = in_sizes[1] / 2;
  const int* src = ei;      // edge_index[0]
  const int* dst = ei + E;  // edge_index[1]

  char* p = (char*)d_ws;
  auto alloc = [&](size_t bytes) {
    void* r = (void*)p;
    p += (bytes + 255) & ~(size_t)255;
    return r;
  };
  int* cursor = (int*)alloc((size_t)N * 4);                         // deg after fill
  int* buck = (int*)alloc((size_t)N * CAP * 4);                     // 25.6 MB
  unsigned short* h1 = (unsigned short*)alloc((size_t)N * FD * 2);  // bf16 h'
  unsigned short* h2 = (unsigned short*)alloc((size_t)N * FD * 2);  // bf16 h'
  short* wf_hi = (short*)alloc((size_t)FD * FD * 2);

  int zB = (N + 255) / 256;
  int wB = FD * FD / 256;  // 64
  int gG = (N + 127) / 128;
  int gA = (N + 3) / 4;
  int gE = (E + 255) / 256;

  // prep: zero cursor | W swizzle (tiny)
  k_prep<<<zB + wB, 256, 0, stream>>>(Wg, wf_hi, cursor, N, zB);
  // single-pass bucketed CSR fill, 1 edge/thread (max waves)
  k_fill<<<gE, 256, 0, stream>>>(src, dst, cursor, buck, E);

  // layer 1 linear: x @ W -> h1 (dis-scaled)
  k_gemm1<<<gG, 256, 0, stream>>>(x, wf_hi, cursor, h1, N);
  // layer 1 agg + layer 2 linear (fused): h1 -> h2
  k_fused<<<gG, 512, 0, stream>>>((const unsigned*)h1, cursor, buck, b, wf_hi, h2, N);
  // layer 2 agg + layer 3 linear (fused): h2 -> h1
  k_fused<<<gG, 512, 0, stream>>>((const unsigned*)h2, cursor, buck, b, wf_hi, h1, N);
  // layer 3 agg -> fp32 output
  k_agg_out<<<gA, 256, 0, stream>>>((const unsigned*)h1, cursor, buck, b,
                                    (float2*)d_out, N);
}

// Round 4
// 302.313 us; speedup vs baseline: 1.1344x; 1.1344x over previous
//
#include <hip/hip_runtime.h>

#define FD 128  // feature dim
#define CAP 64  // bucket slots per node (Poisson(8) degrees; P(deg>64) ~ 0)

typedef __attribute__((ext_vector_type(8))) short short8;   // 8 bf16 in 4 VGPRs
typedef __attribute__((ext_vector_type(4))) float floatx4;  // MFMA acc

__device__ inline unsigned short f2bf(float f) {  // fp32 -> bf16 bits, RNE
  unsigned u = __float_as_uint(f);
  u += 0x7fffu + ((u >> 16) & 1u);
  return (unsigned short)(u >> 16);
}
__device__ inline float lo16f(unsigned v) { return __uint_as_float(v << 16); }
__device__ inline float hi16f(unsigned v) { return __uint_as_float(v & 0xffff0000u); }
__device__ inline int imin(int a, int b) { return a < b ? a : b; }
__device__ inline unsigned umin(unsigned a, unsigned b) { return a < b ? a : b; }

// ---------------- prep: zero cursor | W swizzle->bf16 (no LDS, tiny) --------
// W frag order: idx -> k = kt*32+(lane>>4)*8+j, n = ct*16+(lane&15)
__global__ __launch_bounds__(256) void k_prep(const float* __restrict__ W,
                                              short* __restrict__ whi,
                                              int* __restrict__ cursor, int N,
                                              int zB) {
  int b = blockIdx.x;
  if (b < zB) {
    int i = b * 256 + threadIdx.x;
    if (i < N) cursor[i] = 0;
  } else {
    int idx = (b - zB) * 256 + threadIdx.x;  // 0..16383
    int j = idx & 7, lane = (idx >> 3) & 63, kt = (idx >> 9) & 3, ct = idx >> 11;
    int k = kt * 32 + (lane >> 4) * 8 + j;
    int n = ct * 16 + (lane & 15);
    whi[idx] = (short)f2bf(W[k * FD + n]);
  }
}

// ---------------- bucket fill: single atomic pass, 1 edge/thread ----------
// Latency-bound on the atomic->store chain: maximize waves, not depth.
__global__ __launch_bounds__(256) void k_fill(const int* __restrict__ src,
                                              const int* __restrict__ dst,
                                              int* __restrict__ cursor,
                                              int* __restrict__ buck, int E) {
  int e = blockIdx.x * 256 + threadIdx.x;
  if (e < E) {
    int d = dst[e], s = src[e];
    int pos = atomicAdd(&cursor[d], 1);
    if (pos < CAP) buck[(size_t)d * CAP + pos] = s;
  }
}

// ---------------- GEMM: H'(bf16) = dis[row] * (A @ W) via bf16 MFMA --------
// W fragments in 32 KB LDS. 4 waves/block, 32 rows/wave, 128 rows/block.
// ABF16=false: A fp32, rounded to bf16 in-register.
template <bool ABF16>
__global__ __launch_bounds__(256) void k_gemm(const void* __restrict__ Av,
                                              const short* __restrict__ Wf_hi,
                                              const int* __restrict__ cursor,
                                              unsigned short* __restrict__ H, int N) {
  __shared__ short whi[FD * FD];
  int tid = threadIdx.x;
#pragma unroll
  for (int it = 0; it < 8; ++it) {
    int idx = (it * 256 + tid) * 8;  // 16 B per thread per iter
    *(short8*)&whi[idx] = *(const short8*)&Wf_hi[idx];
  }
  __syncthreads();

  int wid = tid >> 6, lane = tid & 63;
  int quad = lane >> 4, m = lane & 15;
  int rbase = blockIdx.x * 128 + wid * 32;

  short8 ahi[2][4];
#pragma unroll
  for (int t = 0; t < 2; ++t) {
    int arow = rbase + t * 16 + m;
    if (arow >= N) arow = N - 1;  // clamp; OOB rows never stored
    if (ABF16) {
      const unsigned short* ap = (const unsigned short*)Av + (size_t)arow * FD;
#pragma unroll
      for (int kt = 0; kt < 4; ++kt)
        ahi[t][kt] = *(const short8*)(ap + kt * 32 + quad * 8);
    } else {
      const float* ap = (const float*)Av + (size_t)arow * FD;
#pragma unroll
      for (int kt = 0; kt < 4; ++kt) {
        const float* p = ap + kt * 32 + quad * 8;
        float4 a0 = *(const float4*)p;
        float4 a1 = *(const float4*)(p + 4);
        ahi[t][kt][0] = (short)f2bf(a0.x); ahi[t][kt][1] = (short)f2bf(a0.y);
        ahi[t][kt][2] = (short)f2bf(a0.z); ahi[t][kt][3] = (short)f2bf(a0.w);
        ahi[t][kt][4] = (short)f2bf(a1.x); ahi[t][kt][5] = (short)f2bf(a1.y);
        ahi[t][kt][6] = (short)f2bf(a1.z); ahi[t][kt][7] = (short)f2bf(a1.w);
      }
    }
  }

  // per-store-row dis = rsqrt(deg+1); rows wave-uniform per quad -> broadcast
  float dis0[4], dis1[4];
#pragma unroll
  for (int r = 0; r < 4; ++r) {
    int row0 = imin(rbase + quad * 4 + r, N - 1);
    int row1 = imin(rbase + 16 + quad * 4 + r, N - 1);
    dis0[r] = rsqrtf((float)(imin(cursor[row0], CAP) + 1));
    dis1[r] = rsqrtf((float)(imin(cursor[row1], CAP) + 1));
  }

#pragma unroll
  for (int ct = 0; ct < 8; ++ct) {
    floatx4 acc0 = {0.f, 0.f, 0.f, 0.f}, acc1 = {0.f, 0.f, 0.f, 0.f};
#pragma unroll
    for (int kt = 0; kt < 4; ++kt) {
      int fo = (((ct << 2) + kt) * 64 + lane) * 8;
      short8 bhi = *(const short8*)&whi[fo];
      acc0 = __builtin_amdgcn_mfma_f32_16x16x32_bf16(ahi[0][kt], bhi, acc0, 0, 0, 0);
      acc1 = __builtin_amdgcn_mfma_f32_16x16x32_bf16(ahi[1][kt], bhi, acc1, 0, 0, 0);
    }
    // C/D: row = quad*4 + reg, col = lane&15
#pragma unroll
    for (int r = 0; r < 4; ++r) {
      int row0 = rbase + quad * 4 + r;
      int row1 = rbase + 16 + quad * 4 + r;
      if (row0 < N) H[(size_t)row0 * FD + ct * 16 + m] = f2bf(acc0[r] * dis0[r]);
      if (row1 < N) H[(size_t)row1 * FD + ct * 16 + m] = f2bf(acc1[r] * dis1[r]);
    }
  }
}

// ---------------- Aggregation: out = relu(dis_i*(sum h'[src] + h'_i) + b) ----
// 4 NODES PER WAVE, chains interleaved for memory-level parallelism.
// Agg is latency-bound (R1/R2: byte cuts were neutral; R3 counters: all pipes
// <27%): one node/wave = 3 serial round-trips (cursor -> bucket -> gathers)
// for ~10 VMEM ops. Bucket/self addresses depend only on node id, NOT on
// cursor value, so all 4 nodes' metadata (12 VMEM) issues in one batch, then
// all 32 group-0 gathers issue together: ~4x MLP on the dominant path.
// Tail groups (deg>8) run pack-wide per group index under uniform guards.
template <bool OUTBF16>
__global__ __launch_bounds__(256) void k_agg(const unsigned int* __restrict__ h,
                                             const int* __restrict__ cursor,
                                             const int* __restrict__ buck,
                                             const float* __restrict__ bias,
                                             void* __restrict__ out, int N) {
  int wid = threadIdx.x >> 6;
  int lane = threadIdx.x & 63;
  int base = blockIdx.x * 16 + wid * 4;
  if (base >= N) return;

  int node[4];
#pragma unroll
  for (int q = 0; q < 4; ++q) node[q] = imin(base + q, N - 1);

  // ---- batch 1: all metadata + self rows (12 independent VMEM) ----
  int degl[4];
  int4 sa[4], sb[4];
  unsigned v[4];
#pragma unroll
  for (int q = 0; q < 4; ++q) {
    degl[q] = cursor[node[q]];
    const int4* bp = (const int4*)(buck + (size_t)node[q] * CAP);
    sa[q] = bp[0];
    sb[q] = bp[1];
    v[q] = h[(size_t)node[q] * 64 + lane];
  }

  // ---- batch 2: group-0 gathers for all 4 nodes (32 VMEM in flight) ----
  unsigned g[4][8];
#pragma unroll
  for (int q = 0; q < 4; ++q) {
    int srcs[8] = {sa[q].x, sa[q].y, sa[q].z, sa[q].w,
                   sb[q].x, sb[q].y, sb[q].z, sb[q].w};
#pragma unroll
    for (int j = 0; j < 8; ++j) {
      // wave-uniform: pin to SGPR so gather is saddr + lane
      unsigned su = (unsigned)__builtin_amdgcn_readfirstlane(srcs[j]);
      su = umin(su, (unsigned)(N - 1));  // poison-safe
      g[q][j] = h[(size_t)su * 64 + lane];
    }
  }

  int deg[4], nit[4];
  int nmax = 0;
#pragma unroll
  for (int q = 0; q < 4; ++q) {
    deg[q] = __builtin_amdgcn_readfirstlane(imin(degl[q], CAP));
    nit[q] = (deg[q] + 7) >> 3;
    nmax = nit[q] > nmax ? nit[q] : nmax;
  }

  // ---- accumulate group 0 (predicated weights, 2 partial pairs/node) ----
  float s0[4], s1[4], t0[4], t1[4];
#pragma unroll
  for (int q = 0; q < 4; ++q) {
    s0[q] = lo16f(v[q]); s1[q] = hi16f(v[q]);  // self term, weight 1
    t0[q] = 0.f; t1[q] = 0.f;
#pragma unroll
    for (int j = 0; j < 8; ++j) {
      float w = (j < deg[q]) ? 1.f : 0.f;
      float l = lo16f(g[q][j]), hh = hi16f(g[q][j]);
      if (j & 1) { t0[q] = fmaf(w, l, t0[q]); t1[q] = fmaf(w, hh, t1[q]); }
      else       { s0[q] = fmaf(w, l, s0[q]); s1[q] = fmaf(w, hh, s1[q]); }
    }
  }

  // ---- tail groups (deg > 8): pack-wide, uniform scalar guards ----
  for (int it = 1; it < nmax; ++it) {
    unsigned gg[4][8];
#pragma unroll
    for (int q = 0; q < 4; ++q) {
      if (it < nit[q]) {  // wave-uniform guard -> scalar branch
        const int4* bp = (const int4*)(buck + (size_t)node[q] * CAP);
        int4 ta = bp[2 * it];
        int4 tb = bp[2 * it + 1];
        int srcs[8] = {ta.x, ta.y, ta.z, ta.w, tb.x, tb.y, tb.z, tb.w};
#pragma unroll
        for (int j = 0; j < 8; ++j) {
          unsigned su = (unsigned)__builtin_amdgcn_readfirstlane(srcs[j]);
          su = umin(su, (unsigned)(N - 1));  // poison-safe
          gg[q][j] = h[(size_t)su * 64 + lane];
        }
      } else {
#pragma unroll
        for (int j = 0; j < 8; ++j) gg[q][j] = 0;  // contributes exactly 0
      }
    }
#pragma unroll
    for (int q = 0; q < 4; ++q) {
      int done = it * 8;
#pragma unroll
      for (int j = 0; j < 8; ++j) {
        float w = (done + j < deg[q]) ? 1.f : 0.f;
        float l = lo16f(gg[q][j]), hh = hi16f(gg[q][j]);
        if (j & 1) { t0[q] = fmaf(w, l, t0[q]); t1[q] = fmaf(w, hh, t1[q]); }
        else       { s0[q] = fmaf(w, l, s0[q]); s1[q] = fmaf(w, hh, s1[q]); }
      }
    }
  }

  // ---- epilogue: dis scale, bias, relu, store ----
  float2 bb = ((const float2*)bias)[lane];
#pragma unroll
  for (int q = 0; q < 4; ++q) {
    if (base + q < N) {
      float disi = rsqrtf((float)(deg[q] + 1));
      float o0 = fmaxf(fmaf(disi, s0[q] + t0[q], bb.x), 0.f);
      float o1 = fmaxf(fmaf(disi, s1[q] + t1[q], bb.y), 0.f);
      if (OUTBF16) {
        unsigned pk = ((unsigned)f2bf(o1) << 16) | (unsigned)f2bf(o0);
        ((unsigned*)out)[(size_t)(base + q) * 64 + lane] = pk;
      } else {
        ((float2*)out)[(size_t)(base + q) * 64 + lane] = make_float2(o0, o1);
      }
    }
  }
}

// ---------------- launch ----------------

extern "C" void kernel_launch(void* const* d_in, const int* in_sizes, int n_in,
                              void* d_out, int out_size, void* d_ws, size_t ws_size,
                              hipStream_t stream) {
  const float* x = (const float*)d_in[0];
  const int* ei = (const int*)d_in[1];
  const float* Wg = (const float*)d_in[2];
  const float* b = (const float*)d_in[3];
  int N = in_sizes[0] / FD;
  int E = in_sizes[1] / 2;
  const int* src = ei;      // edge_index[0]
  const int* dst = ei + E;  // edge_index[1]

  char* p = (char*)d_ws;
  auto alloc = [&](size_t bytes) {
    void* r = (void*)p;
    p += (bytes + 255) & ~(size_t)255;
    return r;
  };
  int* cursor = (int*)alloc((size_t)N * 4);                        // deg after fill
  int* buck = (int*)alloc((size_t)N * CAP * 4);                    // 25.6 MB
  unsigned short* h = (unsigned short*)alloc((size_t)N * FD * 2);  // bf16 h'
  unsigned short* xb = (unsigned short*)alloc((size_t)N * FD * 2); // bf16 x
  short* wf_hi = (short*)alloc((size_t)FD * FD * 2);

  int zB = (N + 255) / 256;
  int wB = FD * FD / 256;  // 64
  int gG = (N + 127) / 128;
  int gA = (N + 15) / 16;  // 4 waves/block, 4 nodes/wave
  int gE = (E + 255) / 256;

  // prep: zero cursor | W swizzle (tiny)
  k_prep<<<zB + wB, 256, 0, stream>>>(Wg, wf_hi, cursor, N, zB);
  // single-pass bucketed CSR fill, 1 edge/thread (max waves)
  k_fill<<<gE, 256, 0, stream>>>(src, dst, cursor, buck, E);

  // 3 GCN layers: gemm (dis-scaled epilogue) then unweighted gather-aggregate
  k_gemm<false><<<gG, 256, 0, stream>>>(x, wf_hi, cursor, h, N);
  k_agg<true><<<gA, 256, 0, stream>>>((const unsigned*)h, cursor, buck, b, xb, N);
  k_gemm<true><<<gG, 256, 0, stream>>>(xb, wf_hi, cursor, h, N);
  k_agg<true><<<gA, 256, 0, stream>>>((const unsigned*)h, cursor, buck, b, xb, N);
  k_gemm<true><<<gG, 256, 0, stream>>>(xb, wf_hi, cursor, h, N);
  k_agg<false><<<gA, 256, 0, stream>>>((const unsigned*)h, cursor, buck, b, d_out, N);
}

// Round 5
// 294.603 us; speedup vs baseline: 1.1641x; 1.0262x over previous
//
#include <hip/hip_runtime.h>

#define FD 128  // feature dim
#define CAP 64  // bucket slots per node (Poisson(8) degrees; P(deg>64) ~ 0)

typedef __attribute__((ext_vector_type(8))) short short8;   // 8 bf16 in 4 VGPRs
typedef __attribute__((ext_vector_type(4))) float floatx4;  // MFMA acc

__device__ inline unsigned short f2bf(float f) {  // fp32 -> bf16 bits, RNE
  unsigned u = __float_as_uint(f);
  u += 0x7fffu + ((u >> 16) & 1u);
  return (unsigned short)(u >> 16);
}
__device__ inline float lo16f(unsigned v) { return __uint_as_float(v << 16); }
__device__ inline float hi16f(unsigned v) { return __uint_as_float(v & 0xffff0000u); }
__device__ inline int imin(int a, int b) { return a < b ? a : b; }
__device__ inline unsigned umin(unsigned a, unsigned b) { return a < b ? a : b; }

// ---------------- prep: zero cursor | W swizzle->bf16 (no LDS, tiny) --------
// W frag order: idx -> k = kt*32+(lane>>4)*8+j, n = ct*16+(lane&15)
__global__ __launch_bounds__(256) void k_prep(const float* __restrict__ W,
                                              short* __restrict__ whi,
                                              int* __restrict__ cursor, int N,
                                              int zB) {
  int b = blockIdx.x;
  if (b < zB) {
    int i = b * 256 + threadIdx.x;
    if (i < N) cursor[i] = 0;
  } else {
    int idx = (b - zB) * 256 + threadIdx.x;  // 0..16383
    int j = idx & 7, lane = (idx >> 3) & 63, kt = (idx >> 9) & 3, ct = idx >> 11;
    int k = kt * 32 + (lane >> 4) * 8 + j;
    int n = ct * 16 + (lane & 15);
    whi[idx] = (short)f2bf(W[k * FD + n]);
  }
}

// ---------------- bucket fill: XCD-sliced single atomic pass ----------------
// R4 diagnosis: old 1-edge/thread fill wrote 64 B/edge to HBM (WRITE_SIZE
// 47.5 MB for 3.2 MB logical): a bucket line receives its ~8 stores from
// blocks on all 8 XCDs, so per-XCD L2s ping-pong the line and flush a full
// line per 4 B store. Fix: 8 blocks per edge chunk, one per dst-slice
// (slice = (d>>4)&7 -- a 64 B cursor line maps to ONE slice). With the
// round-robin blockIdx%8 -> XCD placement, all stores to a line issue from
// one XCD's L2 and merge before write-back. Cost: edge list read 8x
// (L3-absorbed). Correctness is independent of the XCD mapping.
__global__ __launch_bounds__(256) void k_fill(const int* __restrict__ src,
                                              const int* __restrict__ dst,
                                              int* __restrict__ cursor,
                                              int* __restrict__ buck, int E) {
  int slice = blockIdx.x & 7;  // heuristic: co-locates slice with XCD
  int e = (blockIdx.x >> 3) * 256 + threadIdx.x;
  if (e < E) {
    int d = dst[e];
    if (((d >> 4) & 7) == slice) {
      int s = src[e];
      int pos = atomicAdd(&cursor[d], 1);
      if (pos < CAP) buck[(size_t)d * CAP + pos] = s;
    }
  }
}

// ---------------- GEMM: H'(bf16) = dis[row] * (A @ W) via bf16 MFMA --------
// W fragments in 32 KB LDS. 4 waves/block, 32 rows/wave, 128 rows/block.
// ABF16=false: A fp32, rounded to bf16 in-register.
template <bool ABF16>
__global__ __launch_bounds__(256) void k_gemm(const void* __restrict__ Av,
                                              const short* __restrict__ Wf_hi,
                                              const int* __restrict__ cursor,
                                              unsigned short* __restrict__ H, int N) {
  __shared__ short whi[FD * FD];
  int tid = threadIdx.x;
#pragma unroll
  for (int it = 0; it < 8; ++it) {
    int idx = (it * 256 + tid) * 8;  // 16 B per thread per iter
    *(short8*)&whi[idx] = *(const short8*)&Wf_hi[idx];
  }
  __syncthreads();

  int wid = tid >> 6, lane = tid & 63;
  int quad = lane >> 4, m = lane & 15;
  int rbase = blockIdx.x * 128 + wid * 32;

  short8 ahi[2][4];
#pragma unroll
  for (int t = 0; t < 2; ++t) {
    int arow = rbase + t * 16 + m;
    if (arow >= N) arow = N - 1;  // clamp; OOB rows never stored
    if (ABF16) {
      const unsigned short* ap = (const unsigned short*)Av + (size_t)arow * FD;
#pragma unroll
      for (int kt = 0; kt < 4; ++kt)
        ahi[t][kt] = *(const short8*)(ap + kt * 32 + quad * 8);
    } else {
      const float* ap = (const float*)Av + (size_t)arow * FD;
#pragma unroll
      for (int kt = 0; kt < 4; ++kt) {
        const float* p = ap + kt * 32 + quad * 8;
        float4 a0 = *(const float4*)p;
        float4 a1 = *(const float4*)(p + 4);
        ahi[t][kt][0] = (short)f2bf(a0.x); ahi[t][kt][1] = (short)f2bf(a0.y);
        ahi[t][kt][2] = (short)f2bf(a0.z); ahi[t][kt][3] = (short)f2bf(a0.w);
        ahi[t][kt][4] = (short)f2bf(a1.x); ahi[t][kt][5] = (short)f2bf(a1.y);
        ahi[t][kt][6] = (short)f2bf(a1.z); ahi[t][kt][7] = (short)f2bf(a1.w);
      }
    }
  }

  // per-store-row dis = rsqrt(deg+1); rows wave-uniform per quad -> broadcast
  float dis0[4], dis1[4];
#pragma unroll
  for (int r = 0; r < 4; ++r) {
    int row0 = imin(rbase + quad * 4 + r, N - 1);
    int row1 = imin(rbase + 16 + quad * 4 + r, N - 1);
    dis0[r] = rsqrtf((float)(imin(cursor[row0], CAP) + 1));
    dis1[r] = rsqrtf((float)(imin(cursor[row1], CAP) + 1));
  }

#pragma unroll
  for (int ct = 0; ct < 8; ++ct) {
    floatx4 acc0 = {0.f, 0.f, 0.f, 0.f}, acc1 = {0.f, 0.f, 0.f, 0.f};
#pragma unroll
    for (int kt = 0; kt < 4; ++kt) {
      int fo = (((ct << 2) + kt) * 64 + lane) * 8;
      short8 bhi = *(const short8*)&whi[fo];
      acc0 = __builtin_amdgcn_mfma_f32_16x16x32_bf16(ahi[0][kt], bhi, acc0, 0, 0, 0);
      acc1 = __builtin_amdgcn_mfma_f32_16x16x32_bf16(ahi[1][kt], bhi, acc1, 0, 0, 0);
    }
    // C/D: row = quad*4 + reg, col = lane&15
#pragma unroll
    for (int r = 0; r < 4; ++r) {
      int row0 = rbase + quad * 4 + r;
      int row1 = rbase + 16 + quad * 4 + r;
      if (row0 < N) H[(size_t)row0 * FD + ct * 16 + m] = f2bf(acc0[r] * dis0[r]);
      if (row1 < N) H[(size_t)row1 * FD + ct * 16 + m] = f2bf(acc1[r] * dis1[r]);
    }
  }
}

// ---------------- Aggregation: out = relu(dis_i*(sum h'[src] + h'_i) + b) ----
// One wave per node (round-0 form: best measured; R2 tail-skip and R4
// 4-node MLP variants were both neutral -- agg sits at the random-gather
// line-fill ceiling, not latency or bytes). Bucket srcs readfirstlane'd
// into SGPRs -> gathers are saddr + lane; 8 gathers/iter, predicated.
template <bool OUTBF16>
__global__ __launch_bounds__(256) void k_agg(const unsigned int* __restrict__ h,
                                             const int* __restrict__ cursor,
                                             const int* __restrict__ buck,
                                             const float* __restrict__ bias,
                                             void* __restrict__ out, int N) {
  int wid = __builtin_amdgcn_readfirstlane(threadIdx.x >> 6);  // wave-uniform
  int lane = threadIdx.x & 63;
  int i = blockIdx.x * 4 + wid;
  if (i >= N) return;
  int deg = imin(cursor[i], CAP);
  float disi = rsqrtf((float)(deg + 1));
  unsigned v = h[(size_t)i * 64 + lane];  // h'_i (self term, weight 1)
  float a0 = lo16f(v), a1 = hi16f(v);
  float b0 = 0.f, b1 = 0.f, c0 = 0.f, c1 = 0.f, d0 = 0.f, d1 = 0.f;

  const int4* bp = (const int4*)(buck + (size_t)i * CAP);
  int niter = (deg + 7) >> 3;
  for (int it = 0; it < niter; ++it) {
    int4 sa = bp[2 * it];
    int4 sb = bp[2 * it + 1];
    int srcs[8] = {sa.x, sa.y, sa.z, sa.w, sb.x, sb.y, sb.z, sb.w};
    unsigned g[8];
#pragma unroll
    for (int j = 0; j < 8; ++j) {
      // values are wave-uniform: pin to SGPR so gather is saddr + lane
      unsigned su = (unsigned)__builtin_amdgcn_readfirstlane(srcs[j]);
      su = umin(su, (unsigned)(N - 1));  // poison-safe
      g[j] = h[(size_t)su * 64 + lane];
    }
    int done = it * 8;
#pragma unroll
    for (int j = 0; j < 8; ++j) {
      float w = (done + j < deg) ? 1.f : 0.f;
      float l = lo16f(g[j]), hh = hi16f(g[j]);
      if (j == 0 || j == 4) { a0 = fmaf(w, l, a0); a1 = fmaf(w, hh, a1); }
      else if (j == 1 || j == 5) { b0 = fmaf(w, l, b0); b1 = fmaf(w, hh, b1); }
      else if (j == 2 || j == 6) { c0 = fmaf(w, l, c0); c1 = fmaf(w, hh, c1); }
      else { d0 = fmaf(w, l, d0); d1 = fmaf(w, hh, d1); }
    }
  }

  float2 bb = ((const float2*)bias)[lane];
  float o0 = fmaxf(fmaf(disi, (a0 + b0) + (c0 + d0), bb.x), 0.f);
  float o1 = fmaxf(fmaf(disi, (a1 + b1) + (c1 + d1), bb.y), 0.f);
  if (OUTBF16) {
    unsigned pk = ((unsigned)f2bf(o1) << 16) | (unsigned)f2bf(o0);
    ((unsigned*)out)[(size_t)i * 64 + lane] = pk;
  } else {
    ((float2*)out)[(size_t)i * 64 + lane] = make_float2(o0, o1);
  }
}

// ---------------- launch ----------------

extern "C" void kernel_launch(void* const* d_in, const int* in_sizes, int n_in,
                              void* d_out, int out_size, void* d_ws, size_t ws_size,
                              hipStream_t stream) {
  const float* x = (const float*)d_in[0];
  const int* ei = (const int*)d_in[1];
  const float* Wg = (const float*)d_in[2];
  const float* b = (const float*)d_in[3];
  int N = in_sizes[0] / FD;
  int E = in_sizes[1] / 2;
  const int* src = ei;      // edge_index[0]
  const int* dst = ei + E;  // edge_index[1]

  char* p = (char*)d_ws;
  auto alloc = [&](size_t bytes) {
    void* r = (void*)p;
    p += (bytes + 255) & ~(size_t)255;
    return r;
  };
  int* cursor = (int*)alloc((size_t)N * 4);                        // deg after fill
  int* buck = (int*)alloc((size_t)N * CAP * 4);                    // 25.6 MB
  unsigned short* h = (unsigned short*)alloc((size_t)N * FD * 2);  // bf16 h'
  unsigned short* xb = (unsigned short*)alloc((size_t)N * FD * 2); // bf16 x
  short* wf_hi = (short*)alloc((size_t)FD * FD * 2);

  int zB = (N + 255) / 256;
  int wB = FD * FD / 256;  // 64
  int gG = (N + 127) / 128;
  int gA = (N + 3) / 4;
  int gE = (E + 255) / 256;

  // prep: zero cursor | W swizzle (tiny)
  k_prep<<<zB + wB, 256, 0, stream>>>(Wg, wf_hi, cursor, N, zB);
  // XCD-sliced bucketed CSR fill: 8 slice-blocks per 256-edge chunk
  k_fill<<<8 * gE, 256, 0, stream>>>(src, dst, cursor, buck, E);

  // 3 GCN layers: gemm (dis-scaled epilogue) then unweighted gather-aggregate
  k_gemm<false><<<gG, 256, 0, stream>>>(x, wf_hi, cursor, h, N);
  k_agg<true><<<gA, 256, 0, stream>>>((const unsigned*)h, cursor, buck, b, xb, N);
  k_gemm<true><<<gG, 256, 0, stream>>>(xb, wf_hi, cursor, h, N);
  k_agg<true><<<gA, 256, 0, stream>>>((const unsigned*)h, cursor, buck, b, xb, N);
  k_gemm<true><<<gG, 256, 0, stream>>>(xb, wf_hi, cursor, h, N);
  k_agg<false><<<gA, 256, 0, stream>>>((const unsigned*)h, cursor, buck, b, d_out, N);
}